// Round 2
// baseline (115.731 us; speedup 1.0000x reference)
//
#include <hip/hip_runtime.h>
#include <hip/hip_bf16.h>

typedef __attribute__((ext_vector_type(8))) short bf16x8;
typedef __attribute__((ext_vector_type(16))) float f32x16;

__device__ inline unsigned short f2b(float f) {
  __hip_bfloat16 h = __float2bfloat16(f);
  unsigned short u;
  __builtin_memcpy(&u, &h, sizeof(u));
  return u;
}
__device__ inline unsigned int pk2(float lo, float hi) {
  return (unsigned int)f2b(lo) | ((unsigned int)f2b(hi) << 16);
}

constexpr int S_LEN = 2048;
constexpr int DIM   = 64;
constexpr int QB    = 64;   // q rows per block (32 per wave)
constexpr int KB    = 64;   // kv rows per iteration
constexpr int LDK   = 72;   // padded LDS row (bf16 elems)
constexpr float SC_LOG2E = 0.125f * 1.44269504088896f;

__global__ __launch_bounds__(128)
void attn_fwd(const float* __restrict__ x1, const float* __restrict__ x2,
              float* __restrict__ out) {
  __shared__ unsigned short smem[2 * KB * LDK];
  unsigned short (*Kl)[LDK] = reinterpret_cast<unsigned short (*)[LDK]>(smem);            // [k][d]
  unsigned short (*Vt)[LDK] = reinterpret_cast<unsigned short (*)[LDK]>(smem + KB * LDK); // [d][k]

  const int bid  = blockIdx.x;
  const int b    = bid >> 5;          // 32 q-blocks per batch
  const int q0   = (bid & 31) * QB;
  const int tid  = threadIdx.x;
  const int wid  = tid >> 6;          // wave 0/1
  const int lane = tid & 63;
  const int r    = lane & 31;
  const int hi   = lane >> 5;

  const float* Qp     = x1 + ((size_t)b * S_LEN + q0 + wid * 32 + r) * DIM;
  const float* KVbase = x2 + (size_t)b * S_LEN * DIM;

  // Q as B-operand (Q^T): qf[c][j] = Q[q=r][16c + 8*hi + j]
  bf16x8 qf[4];
  #pragma unroll
  for (int c = 0; c < 4; ++c) {
    const float* p = Qp + 16 * c + 8 * hi;
    bf16x8 v;
    #pragma unroll
    for (int j = 0; j < 8; ++j) v[j] = (short)f2b(p[j]);
    qf[c] = v;
  }

  f32x16 oacc[2];
  #pragma unroll
  for (int i = 0; i < 16; ++i) { oacc[0][i] = 0.f; oacc[1][i] = 0.f; }
  float m_run = -3.0e38f;
  float lsum  = 0.f;

  for (int t = 0; t < S_LEN / KB; ++t) {
    __syncthreads();
    // stage K(=V) tile: fp32 -> bf16, row-major [k][d] AND transposed [d][k]
    const float* src = KVbase + (size_t)t * KB * DIM;
    #pragma unroll
    for (int it = 0; it < (KB * DIM / 4) / 128; ++it) {
      int s   = tid + it * 128;
      int row = s >> 4;
      int c4  = (s & 15) * 4;
      float4 v = *reinterpret_cast<const float4*>(src + row * DIM + c4);
      ushort4 u;
      u.x = f2b(v.x); u.y = f2b(v.y); u.z = f2b(v.z); u.w = f2b(v.w);
      *reinterpret_cast<ushort4*>(&Kl[row][c4]) = u;
      Vt[c4 + 0][row] = u.x;
      Vt[c4 + 1][row] = u.y;
      Vt[c4 + 2][row] = u.z;
      Vt[c4 + 3][row] = u.w;
    }
    __syncthreads();

    // S^T = K * Q^T : two 32x32 tiles (kt), K-dim = 64 via 4 chunks
    f32x16 st[2];
    #pragma unroll
    for (int kt = 0; kt < 2; ++kt) {
      f32x16 acc;
      #pragma unroll
      for (int i = 0; i < 16; ++i) acc[i] = 0.f;
      #pragma unroll
      for (int c = 0; c < 4; ++c) {
        bf16x8 a = *reinterpret_cast<const bf16x8*>(&Kl[kt * 32 + r][16 * c + 8 * hi]);
        acc = __builtin_amdgcn_mfma_f32_32x32x16_bf16(a, qf[c], acc, 0, 0, 0);
      }
      st[kt] = acc;
    }

    // online softmax (per lane: one q-column, 32 k-values; partner lane has other 32)
    float mx = st[0][0];
    #pragma unroll
    for (int i = 1; i < 16; ++i) mx = fmaxf(mx, st[0][i]);
    #pragma unroll
    for (int i = 0; i < 16; ++i) mx = fmaxf(mx, st[1][i]);
    mx = fmaxf(mx, __shfl_xor(mx, 32));
    float mnew  = fmaxf(m_run, mx);
    float alpha = exp2f((m_run - mnew) * SC_LOG2E);
    m_run = mnew;
    float mc = mnew * SC_LOG2E;
    float p[32];
    float psum = 0.f;
    #pragma unroll
    for (int kt = 0; kt < 2; ++kt) {
      #pragma unroll
      for (int i = 0; i < 16; ++i) {
        float e = exp2f(fmaf(st[kt][i], SC_LOG2E, -mc));
        p[kt * 16 + i] = e;
        psum += e;
      }
    }
    psum += __shfl_xor(psum, 32);
    lsum = lsum * alpha + psum;
    #pragma unroll
    for (int i = 0; i < 16; ++i) { oacc[0][i] *= alpha; oacc[1][i] *= alpha; }

    // P^T -> bf16 frags in-register (pack + half-swap), then O^T += V^T * P^T
    #pragma unroll
    for (int kt = 0; kt < 2; ++kt) {
      unsigned int own[8], cross[8];
      #pragma unroll
      for (int a = 0; a < 4; ++a) {
        own[a * 2 + 0] = pk2(p[kt * 16 + 4 * a + 0], p[kt * 16 + 4 * a + 1]);
        own[a * 2 + 1] = pk2(p[kt * 16 + 4 * a + 2], p[kt * 16 + 4 * a + 3]);
      }
      #pragma unroll
      for (int e = 0; e < 8; ++e) cross[e] = __shfl_xor(own[e], 32);
      #pragma unroll
      for (int kc = 0; kc < 2; ++kc) {
        union { unsigned int u[4]; bf16x8 v; } pf;
        pf.u[0] = hi ? cross[4 * kc + 2] : own[4 * kc + 0];
        pf.u[1] = hi ? cross[4 * kc + 3] : own[4 * kc + 1];
        pf.u[2] = hi ? own[4 * kc + 2]   : cross[4 * kc + 0];
        pf.u[3] = hi ? own[4 * kc + 3]   : cross[4 * kc + 1];
        #pragma unroll
        for (int dt = 0; dt < 2; ++dt) {
          bf16x8 vf = *reinterpret_cast<const bf16x8*>(
              &Vt[dt * 32 + r][kt * 32 + kc * 16 + 8 * hi]);
          oacc[dt] = __builtin_amdgcn_mfma_f32_32x32x16_bf16(vf, pf.v, oacc[dt], 0, 0, 0);
        }
      }
    }
  }

  // epilogue: O^T regs -> LDS transpose -> coalesced fp32 stores
  __syncthreads();
  float inv = 1.0f / lsum;
  float* Ob = reinterpret_cast<float*>(smem);  // [64 q][65] floats = 16.6 KB <= 18.4 KB
  #pragma unroll
  for (int dt = 0; dt < 2; ++dt) {
    #pragma unroll
    for (int i = 0; i < 16; ++i) {
      int d = dt * 32 + (i & 3) + 8 * (i >> 2) + 4 * hi;
      Ob[(wid * 32 + r) * 65 + d] = oacc[dt][i] * inv;
    }
  }
  __syncthreads();
  float* outp = out + ((size_t)b * S_LEN + q0) * DIM;
  #pragma unroll
  for (int it = 0; it < (QB * DIM / 4) / 128; ++it) {
    int s   = tid + it * 128;
    int row = s >> 4;
    int c4  = (s & 15) * 4;
    float4 v;
    v.x = Ob[row * 65 + c4 + 0];
    v.y = Ob[row * 65 + c4 + 1];
    v.z = Ob[row * 65 + c4 + 2];
    v.w = Ob[row * 65 + c4 + 3];
    *reinterpret_cast<float4*>(outp + row * DIM + c4) = v;
  }
}

extern "C" void kernel_launch(void* const* d_in, const int* in_sizes, int n_in,
                              void* d_out, int out_size, void* d_ws, size_t ws_size,
                              hipStream_t stream) {
  const float* x1 = (const float*)d_in[0];
  const float* x2 = (const float*)d_in[1];
  float* outp = (float*)d_out;
  dim3 grid(16 * (S_LEN / QB));  // 512 blocks
  attn_fwd<<<grid, 128, 0, stream>>>(x1, x2, outp);
}

// Round 3
// 49.320 us; speedup vs baseline: 2.3465x; 2.3465x over previous
//
#include <hip/hip_runtime.h>
#include <hip/hip_bf16.h>

typedef __attribute__((ext_vector_type(8))) short bf16x8;
typedef __attribute__((ext_vector_type(16))) float f32x16;

__device__ inline unsigned short f2b(float f) {
  __hip_bfloat16 h = __float2bfloat16(f);
  unsigned short u; __builtin_memcpy(&u, &h, sizeof(u));
  return u;
}
__device__ inline unsigned int pk2(float lo, float hi) {
  return (unsigned int)f2b(lo) | ((unsigned int)f2b(hi) << 16);
}

constexpr int S_LEN = 2048;
constexpr int DIM   = 64;
constexpr int QB    = 64;   // q rows per block
constexpr int KB    = 64;   // kv rows per iteration per pair
constexpr int LDK   = 72;   // ushorts per LDS row (144 B, 16B-aligned rows)
constexpr int NPAIR = 4;    // wave-pairs splitting the KV range
constexpr int ITERS = S_LEN / KB / NPAIR;  // 8
constexpr float SC_LOG2E = 0.125f * 1.44269504088896f;

__global__ __launch_bounds__(512, 4)
void attn_fwd(const float* __restrict__ x1, const float* __restrict__ x2,
              float* __restrict__ out) {
  __shared__ unsigned short smem[NPAIR * 2 * KB * LDK];  // 73728 B (reused for combine)
  __shared__ float mlbuf[NPAIR][2][QB];                   // 2 KB

  const int bid  = blockIdx.x;
  const int b    = bid >> 5;
  const int q0   = (bid & 31) * QB;
  const int tid  = threadIdx.x;
  const int wave = tid >> 6;
  const int pair = wave >> 1;
  const int wid  = wave & 1;
  const int lane = tid & 63;
  const int r    = lane & 31;
  const int hi   = lane >> 5;
  const int tp   = tid & 127;   // thread within pair

  unsigned short* Kl = smem + pair * (2 * KB * LDK);       // [64][72] k-major
  unsigned char*  Vb = (unsigned char*)(Kl + KB * LDK);    // V^T, XOR-swizzled rows

  const float* Qp     = x1 + ((size_t)b * S_LEN + q0 + wid * 32 + r) * DIM;
  const float* KVbase = x2 + (size_t)b * S_LEN * DIM;

  // Q as B-operand: qf[c][j] = Q[q=r][16c + 8hi + j]
  bf16x8 qf[4];
  #pragma unroll
  for (int c = 0; c < 4; ++c) {
    const float* p = Qp + 16 * c + 8 * hi;
    bf16x8 v;
    #pragma unroll
    for (int j = 0; j < 8; ++j) v[j] = (short)f2b(p[j]);
    qf[c] = v;
  }

  f32x16 oacc[2];
  #pragma unroll
  for (int i = 0; i < 16; ++i) { oacc[0][i] = 0.f; oacc[1][i] = 0.f; }
  float m_run = -3.0e38f;
  float lsum  = 0.f;

  for (int t = 0; t < ITERS; ++t) {
    __syncthreads();
    // ---- stage this pair's 64x64 tile: 4x4 register transpose, vector LDS writes
    const float* src = KVbase + (size_t)(pair * ITERS + t) * KB * DIM;
    #pragma unroll
    for (int sb = 0; sb < 2; ++sb) {
      int s    = tp + sb * 128;
      int rowg = s >> 4;
      int colg = s & 15;
      float4 v0 = *reinterpret_cast<const float4*>(src + (4 * rowg + 0) * DIM + 4 * colg);
      float4 v1 = *reinterpret_cast<const float4*>(src + (4 * rowg + 1) * DIM + 4 * colg);
      float4 v2 = *reinterpret_cast<const float4*>(src + (4 * rowg + 2) * DIM + 4 * colg);
      float4 v3 = *reinterpret_cast<const float4*>(src + (4 * rowg + 3) * DIM + 4 * colg);
      unsigned short us[4][4];
      us[0][0]=f2b(v0.x); us[0][1]=f2b(v0.y); us[0][2]=f2b(v0.z); us[0][3]=f2b(v0.w);
      us[1][0]=f2b(v1.x); us[1][1]=f2b(v1.y); us[1][2]=f2b(v1.z); us[1][3]=f2b(v1.w);
      us[2][0]=f2b(v2.x); us[2][1]=f2b(v2.y); us[2][2]=f2b(v2.z); us[2][3]=f2b(v2.w);
      us[3][0]=f2b(v3.x); us[3][1]=f2b(v3.y); us[3][2]=f2b(v3.z); us[3][3]=f2b(v3.w);
      #pragma unroll
      for (int i = 0; i < 4; ++i) {  // K row-major
        ushort4 u; u.x = us[i][0]; u.y = us[i][1]; u.z = us[i][2]; u.w = us[i][3];
        *reinterpret_cast<ushort4*>(&Kl[(4 * rowg + i) * LDK + 4 * colg]) = u;
      }
      int key = (colg & 7) << 4;     // = ((d>>2)&7)<<4 for d = 4*colg+i
      #pragma unroll
      for (int i = 0; i < 4; ++i) {  // V^T swizzled
        int d = 4 * colg + i;
        ushort4 u; u.x = us[0][i]; u.y = us[1][i]; u.z = us[2][i]; u.w = us[3][i];
        *reinterpret_cast<ushort4*>(Vb + d * 144 + ((8 * rowg) ^ key)) = u;
      }
    }
    __syncthreads();

    // ---- S^T = K * Q^T
    f32x16 st[2];
    #pragma unroll
    for (int kt = 0; kt < 2; ++kt) {
      f32x16 acc;
      #pragma unroll
      for (int i = 0; i < 16; ++i) acc[i] = 0.f;
      #pragma unroll
      for (int c = 0; c < 4; ++c) {
        bf16x8 a = *reinterpret_cast<const bf16x8*>(&Kl[(kt * 32 + r) * LDK + 16 * c + 8 * hi]);
        acc = __builtin_amdgcn_mfma_f32_32x32x16_bf16(a, qf[c], acc, 0, 0, 0);
      }
      st[kt] = acc;
    }

    // ---- online softmax (lane owns one q-column; partner half-wave has other 32 k)
    float mx = st[0][0];
    #pragma unroll
    for (int i = 1; i < 16; ++i) mx = fmaxf(mx, st[0][i]);
    #pragma unroll
    for (int i = 0; i < 16; ++i) mx = fmaxf(mx, st[1][i]);
    mx = fmaxf(mx, __shfl_xor(mx, 32));
    float mnew  = fmaxf(m_run, mx);
    float alpha = exp2f((m_run - mnew) * SC_LOG2E);
    m_run = mnew;
    float mc = mnew * SC_LOG2E;
    float psum = 0.f;
    #pragma unroll
    for (int kt = 0; kt < 2; ++kt) {
      #pragma unroll
      for (int i = 0; i < 16; ++i) {
        float e = exp2f(fmaf(st[kt][i], SC_LOG2E, -mc));
        st[kt][i] = e;   // st now holds P
        psum += e;
      }
    }
    psum += __shfl_xor(psum, 32);
    lsum = lsum * alpha + psum;
    #pragma unroll
    for (int i = 0; i < 16; ++i) { oacc[0][i] *= alpha; oacc[1][i] *= alpha; }

    // ---- P^T -> bf16 frags in-register, O^T += V^T * P^T
    int vkey = ((r >> 2) & 7) << 4;
    #pragma unroll
    for (int kt = 0; kt < 2; ++kt) {
      unsigned int own[8], cross[8];
      #pragma unroll
      for (int a = 0; a < 4; ++a) {
        own[a * 2 + 0] = pk2(st[kt][4 * a + 0], st[kt][4 * a + 1]);
        own[a * 2 + 1] = pk2(st[kt][4 * a + 2], st[kt][4 * a + 3]);
      }
      #pragma unroll
      for (int e = 0; e < 8; ++e) cross[e] = __shfl_xor(own[e], 32);
      #pragma unroll
      for (int kc = 0; kc < 2; ++kc) {
        union { unsigned int u[4]; bf16x8 v; } pf;
        pf.u[0] = hi ? cross[4 * kc + 2] : own[4 * kc + 0];
        pf.u[1] = hi ? cross[4 * kc + 3] : own[4 * kc + 1];
        pf.u[2] = hi ? own[4 * kc + 2]   : cross[4 * kc + 0];
        pf.u[3] = hi ? own[4 * kc + 3]   : cross[4 * kc + 1];
        #pragma unroll
        for (int dt = 0; dt < 2; ++dt) {
          bf16x8 vf = *reinterpret_cast<const bf16x8*>(
              Vb + (dt * 32 + r) * 144 + ((kt * 64 + kc * 32 + 16 * hi) ^ vkey));
          oacc[dt] = __builtin_amdgcn_mfma_f32_32x32x16_bf16(vf, pf.v, oacc[dt], 0, 0, 0);
        }
      }
    }
  }

  // ---- combine the 4 pairs' partials (reuse staging LDS, all fp32)
  __syncthreads();
  if (hi == 0) {
    mlbuf[pair][0][wid * 32 + r] = m_run;
    mlbuf[pair][1][wid * 32 + r] = lsum;
  }
  float* Ocomb = reinterpret_cast<float*>(smem);  // [NPAIR][QB][66] = 67584 B
  #pragma unroll
  for (int dt = 0; dt < 2; ++dt) {
    #pragma unroll
    for (int i = 0; i < 16; ++i) {
      int d = dt * 32 + (i & 3) + 8 * (i >> 2) + 4 * hi;
      Ocomb[(pair * QB + wid * 32 + r) * 66 + d] = oacc[dt][i];
    }
  }
  __syncthreads();

  int q  = tid >> 3;
  int dg = tid & 7;
  float m0 = mlbuf[0][0][q], m1 = mlbuf[1][0][q], m2 = mlbuf[2][0][q], m3 = mlbuf[3][0][q];
  float l0 = mlbuf[0][1][q], l1 = mlbuf[1][1][q], l2 = mlbuf[2][1][q], l3 = mlbuf[3][1][q];
  float ms = fmaxf(fmaxf(m0, m1), fmaxf(m2, m3));
  float w0 = exp2f((m0 - ms) * SC_LOG2E);
  float w1 = exp2f((m1 - ms) * SC_LOG2E);
  float w2 = exp2f((m2 - ms) * SC_LOG2E);
  float w3 = exp2f((m3 - ms) * SC_LOG2E);
  float inv = 1.0f / (l0 * w0 + l1 * w1 + l2 * w2 + l3 * w3);
  float o[8];
  #pragma unroll
  for (int j = 0; j < 8; ++j) {
    o[j] = (Ocomb[(0 * QB + q) * 66 + dg * 8 + j] * w0 +
            Ocomb[(1 * QB + q) * 66 + dg * 8 + j] * w1 +
            Ocomb[(2 * QB + q) * 66 + dg * 8 + j] * w2 +
            Ocomb[(3 * QB + q) * 66 + dg * 8 + j] * w3) * inv;
  }
  float* outp = out + ((size_t)b * S_LEN + q0 + q) * DIM + dg * 8;
  float4 s0; s0.x = o[0]; s0.y = o[1]; s0.z = o[2]; s0.w = o[3];
  float4 s1; s1.x = o[4]; s1.y = o[5]; s1.z = o[6]; s1.w = o[7];
  *reinterpret_cast<float4*>(outp + 0) = s0;
  *reinterpret_cast<float4*>(outp + 4) = s1;
}

extern "C" void kernel_launch(void* const* d_in, const int* in_sizes, int n_in,
                              void* d_out, int out_size, void* d_ws, size_t ws_size,
                              hipStream_t stream) {
  const float* x1 = (const float*)d_in[0];
  const float* x2 = (const float*)d_in[1];
  float* outp = (float*)d_out;
  dim3 grid(16 * (S_LEN / QB));  // 512 blocks, 512 threads (8 waves)
  attn_fwd<<<grid, 512, 0, stream>>>(x1, x2, outp);
}